// Round 7
// baseline (238.007 us; speedup 1.0000x reference)
//
#include <hip/hip_runtime.h>
#include <hip/hip_bf16.h>

// loss = (1/N) * [ sum_i softplus(-s_ii) + sum_{i!=j} softplus(s_ij) ] + ln2
// S = E E^T, N=16384, D=128.
// E pre-scaled by sqrt(log2e) in the bf16 cast -> scores in log2 domain;
// softplus*log2e = max(v,0) + log2(1+2^-|v|), log2(1+u) ~= u*P(u) cubic.
// ZERO-LDS design: E(bf16) is 4 MiB = L2-resident on every XCD, so MFMA
// fragments are loaded straight from global (16 rows x 64B = coalesced 1KB
// per instruction). No staging, no barriers, no vmcnt(0) drain (m169/m233
// lesson: don't LDS-stage L2-fit data). Occupancy 24 waves/CU via
// __launch_bounds__(512,6). Triangular tile grid, fused epilogue, 1 atomic.

#define N_DOCS 16384
#define DIM 128
#define NTILE 128          // N_DOCS / 128
#define NTRI (NTILE * (NTILE + 1) / 2)  // 8256

typedef __attribute__((ext_vector_type(8))) __bf16 bf16x8;
typedef __attribute__((ext_vector_type(4))) float f32x4;

#define SQRT_LOG2E 1.2011224087864498f
#define LN2F 0.6931471805599453f
// log2(1+u) ~= u*(C0 + C1*u + C2*u^2) on u in [0,1]
#define PC0 1.43500f
#define PC1 (-0.62967f)
#define PC2 0.19907f

#if __has_builtin(__builtin_amdgcn_exp2f)
#define EXP2F(x) __builtin_amdgcn_exp2f(x)
#else
#define EXP2F(x) exp2f(x)
#endif

__device__ __forceinline__ unsigned short f2bf(float f) {
  unsigned int u = __float_as_uint(f);
  u += 0x7fffu + ((u >> 16) & 1u);  // round-to-nearest-even
  return (unsigned short)(u >> 16);
}

__global__ void cast_kernel(const float* __restrict__ in, unsigned short* __restrict__ out,
                            float* __restrict__ accum) {
  int i = blockIdx.x * blockDim.x + threadIdx.x;
  if (i == 0) accum[0] = 0.f;  // stream-ordered before loss_kernel
  float4 v = reinterpret_cast<const float4*>(in)[i];
  ushort4 o;
  o.x = f2bf(v.x * SQRT_LOG2E); o.y = f2bf(v.y * SQRT_LOG2E);
  o.z = f2bf(v.z * SQRT_LOG2E); o.w = f2bf(v.w * SQRT_LOG2E);
  reinterpret_cast<ushort4*>(out)[i] = o;
}

template <bool FROM_BF16>
__global__ __launch_bounds__(512, 6) void loss_kernel(const void* __restrict__ src,
                                                      float* __restrict__ accum) {
  // triangular decode: block b -> (tr, tc), tr <= tc
  const int b = blockIdx.x;
  int tr = (int)((2 * NTILE + 1 - sqrtf((float)((2 * NTILE + 1) * (2 * NTILE + 1)) - 8.0f * (float)b)) * 0.5f);
  while (tr * NTILE - tr * (tr - 1) / 2 > b) --tr;
  while ((tr + 1) * NTILE - (tr + 1) * tr / 2 <= b) ++tr;
  const int tc = tr + (b - (tr * NTILE - tr * (tr - 1) / 2));

  __shared__ float red[8];
  const int tid = threadIdx.x;
  const int wid = tid >> 6;
  const int lane = tid & 63;
  const int wm = wid >> 2, wn = wid & 3;  // 2x4 waves: 64x32 output each
  const int lrow = lane & 15;             // row within 16-row fragment
  const int kgrp = lane >> 4;             // 8-elem k-group

  f32x4 acc[4][2];
#pragma unroll
  for (int a = 0; a < 4; ++a)
#pragma unroll
    for (int c = 0; c < 2; ++c) acc[a][c] = (f32x4){0.f, 0.f, 0.f, 0.f};

  if constexpr (FROM_BF16) {
    // bf16 slab: row = 256 B. Fragment at (row, k-slice): 16 B contiguous.
    const unsigned char* pa = (const unsigned char*)src + (size_t)tr * 32768 +
                              (wm * 64 + lrow) * 256 + kgrp * 16;
    const unsigned char* pb = (const unsigned char*)src + (size_t)tc * 32768 +
                              (wn * 32 + lrow) * 256 + kgrp * 16;
#pragma unroll
    for (int ks = 0; ks < 4; ++ks) {
      bf16x8 af[4], bfr[2];
#pragma unroll
      for (int f = 0; f < 4; ++f)
        af[f] = *reinterpret_cast<const bf16x8*>(pa + f * 16 * 256 + ks * 64);
#pragma unroll
      for (int f = 0; f < 2; ++f)
        bfr[f] = *reinterpret_cast<const bf16x8*>(pb + f * 16 * 256 + ks * 64);
#pragma unroll
      for (int fm = 0; fm < 4; ++fm)
#pragma unroll
        for (int fn = 0; fn < 2; ++fn)
          acc[fm][fn] = __builtin_amdgcn_mfma_f32_16x16x32_bf16(af[fm], bfr[fn], acc[fm][fn], 0, 0, 0);
    }
  } else {
    // fallback: fp32 direct from input, convert+scale in-register
    const float* basep = (const float*)src;
    const float* pa = basep + (size_t)tr * 16384 + (wm * 64 + lrow) * 128 + kgrp * 8;
    const float* pb = basep + (size_t)tc * 16384 + (wn * 32 + lrow) * 128 + kgrp * 8;
#pragma unroll
    for (int ks = 0; ks < 4; ++ks) {
      bf16x8 af[4], bfr[2];
#pragma unroll
      for (int f = 0; f < 4; ++f) {
        float4 lo = *reinterpret_cast<const float4*>(pa + f * 16 * 128 + ks * 32);
        float4 hi = *reinterpret_cast<const float4*>(pa + f * 16 * 128 + ks * 32 + 4);
        ushort4 ulo = {f2bf(lo.x * SQRT_LOG2E), f2bf(lo.y * SQRT_LOG2E),
                       f2bf(lo.z * SQRT_LOG2E), f2bf(lo.w * SQRT_LOG2E)};
        ushort4 uhi = {f2bf(hi.x * SQRT_LOG2E), f2bf(hi.y * SQRT_LOG2E),
                       f2bf(hi.z * SQRT_LOG2E), f2bf(hi.w * SQRT_LOG2E)};
        struct { ushort4 a, b; } pack{ulo, uhi};
        af[f] = *reinterpret_cast<const bf16x8*>(&pack);
      }
#pragma unroll
      for (int f = 0; f < 2; ++f) {
        float4 lo = *reinterpret_cast<const float4*>(pb + f * 16 * 128 + ks * 32);
        float4 hi = *reinterpret_cast<const float4*>(pb + f * 16 * 128 + ks * 32 + 4);
        ushort4 ulo = {f2bf(lo.x * SQRT_LOG2E), f2bf(lo.y * SQRT_LOG2E),
                       f2bf(lo.z * SQRT_LOG2E), f2bf(lo.w * SQRT_LOG2E)};
        ushort4 uhi = {f2bf(hi.x * SQRT_LOG2E), f2bf(hi.y * SQRT_LOG2E),
                       f2bf(hi.z * SQRT_LOG2E), f2bf(hi.w * SQRT_LOG2E)};
        struct { ushort4 a, b; } pack{ulo, uhi};
        bfr[f] = *reinterpret_cast<const bf16x8*>(&pack);
      }
#pragma unroll
      for (int fm = 0; fm < 4; ++fm)
#pragma unroll
        for (int fn = 0; fn < 2; ++fn)
          acc[fm][fn] = __builtin_amdgcn_mfma_f32_16x16x32_bf16(af[fm], bfr[fn], acc[fm][fn], 0, 0, 0);
    }
  }

  // Epilogue in log2 domain. C/D layout: col = lane&15, row = (lane>>4)*4+reg.
  float sm = 0.f, sp = 0.f;
  if (tr == tc) {
#pragma unroll
    for (int fm = 0; fm < 4; ++fm)
#pragma unroll
      for (int fn = 0; fn < 2; ++fn)
#pragma unroll
        for (int r = 0; r < 4; ++r) {
          float v = acc[fm][fn][r];
          int il = wm * 64 + fm * 16 + kgrp * 4 + r;
          int jl = wn * 32 + fn * 16 + lrow;
          if (il == jl) v = -v;
          sm += fmaxf(v, 0.f);
          float u = EXP2F(-fabsf(v));
          sp = fmaf(u, fmaf(u, fmaf(u, PC2, PC1), PC0), sp);
        }
  } else {
#pragma unroll
    for (int fm = 0; fm < 4; ++fm)
#pragma unroll
      for (int fn = 0; fn < 2; ++fn)
#pragma unroll
        for (int r = 0; r < 4; ++r) {
          float v = acc[fm][fn][r];
          sm += fmaxf(v, 0.f);
          float u = EXP2F(-fabsf(v));
          sp = fmaf(u, fmaf(u, fmaf(u, PC2, PC1), PC0), sp);
        }
    sm *= 2.f;  // symmetric twin tile
    sp *= 2.f;
  }

  float lsum = sm + sp;
#pragma unroll
  for (int off = 32; off > 0; off >>= 1) lsum += __shfl_down(lsum, off);

  if (lane == 0) red[wid] = lsum;
  __syncthreads();
  if (tid == 0) {
    float t = red[0] + red[1] + red[2] + red[3] + red[4] + red[5] + red[6] + red[7];
    atomicAdd(accum, t);
  }
}

__global__ void finalize_kernel(const float* __restrict__ accum, float* __restrict__ out) {
  // accum is in log2 units: loss = ln2 * (accum/N + 1)
  out[0] = LN2F * (accum[0] * (1.0f / (float)N_DOCS) + 1.0f);
}

extern "C" void kernel_launch(void* const* d_in, const int* in_sizes, int n_in,
                              void* d_out, int out_size, void* d_ws, size_t ws_size,
                              hipStream_t stream) {
  const float* E = (const float*)d_in[0];
  float* out = (float*)d_out;
  float* accum = (float*)d_ws;  // 4 B

  const size_t need = 256 + (size_t)N_DOCS * DIM * sizeof(unsigned short);  // ~4 MiB
  if (ws_size >= need) {
    unsigned short* ebf = (unsigned short*)((char*)d_ws + 256);
    cast_kernel<<<(N_DOCS * DIM / 4) / 256, 256, 0, stream>>>(E, ebf, accum);
    loss_kernel<true><<<NTRI, 512, 0, stream>>>(ebf, accum);
  } else {
    (void)hipMemsetAsync(accum, 0, sizeof(float), stream);
    loss_kernel<false><<<NTRI, 512, 0, stream>>>(E, accum);
  }
  finalize_kernel<<<1, 1, 0, stream>>>(accum, out);
}

// Round 8
// 216.512 us; speedup vs baseline: 1.0993x; 1.0993x over previous
//
#include <hip/hip_runtime.h>
#include <hip/hip_bf16.h>

// loss = (1/N) * [ sum_i softplus(-s_ii) + sum_{i!=j} softplus(s_ij) ] + ln2
// S = E E^T, N=16384, D=128.
// E pre-scaled by sqrt(log2e) in the bf16 cast -> scores in log2 domain;
// softplus*log2e = max(v,0) + log2(1+2^-|v|), log2(1+u) ~= u*(QC0+QC1*u).
// HYBRID: B-tile LDS-staged (32KB, XOR-swizzled), A-fragments straight from
// global (L2-resident; 4-way L1 reuse inside the block). 4 blocks/CU.
// Triangular tile grid (8256 blocks), 512 threads (2x4 waves, 64x32 each).
// 64 padded atomic buckets, tiny finalize kernel.

#define N_DOCS 16384
#define DIM 128
#define NTILE 128          // N_DOCS / 128
#define NTRI (NTILE * (NTILE + 1) / 2)  // 8256

typedef __attribute__((ext_vector_type(8))) __bf16 bf16x8;
typedef __attribute__((ext_vector_type(4))) float f32x4;

typedef const __attribute__((address_space(1))) unsigned char* gptr_t;
typedef __attribute__((address_space(3))) unsigned char* lptr_t;

#define SQRT_LOG2E 1.2011224087864498f
#define LN2F 0.6931471805599453f
// log2(1+u) ~= u*(QC0 + QC1*u) on [0,1]; |err|<=0.0082 log2-units
#define QC0 1.33985f
#define QC1 (-0.33985f)

#if __has_builtin(__builtin_amdgcn_exp2f)
#define EXP2F(x) __builtin_amdgcn_exp2f(x)
#else
#define EXP2F(x) exp2f(x)
#endif

#define NBUCKET 64
#define BSTRIDE 16  // floats: 64B-padded buckets to avoid line contention

__device__ __forceinline__ unsigned short f2bf(float f) {
  unsigned int u = __float_as_uint(f);
  u += 0x7fffu + ((u >> 16) & 1u);  // round-to-nearest-even
  return (unsigned short)(u >> 16);
}

__global__ void cast_kernel(const float* __restrict__ in, unsigned short* __restrict__ out,
                            float* __restrict__ buckets) {
  int i = blockIdx.x * blockDim.x + threadIdx.x;
  if (blockIdx.x == 0 && threadIdx.x < NBUCKET) buckets[threadIdx.x * BSTRIDE] = 0.f;
  float4 v = reinterpret_cast<const float4*>(in)[i];
  ushort4 o;
  o.x = f2bf(v.x * SQRT_LOG2E); o.y = f2bf(v.y * SQRT_LOG2E);
  o.z = f2bf(v.z * SQRT_LOG2E); o.w = f2bf(v.w * SQRT_LOG2E);
  reinterpret_cast<ushort4*>(out)[i] = o;
}

// Swizzle involution: physical LDS byte p holds logical byte p^(((p>>8)&7)<<4);
// read side applies the same XOR (bits 4..6 only, below the 256B row stride).

template <bool FROM_BF16>
__global__ __launch_bounds__(512, 8) void loss_kernel(const void* __restrict__ src,
                                                      float* __restrict__ buckets) {
  // triangular decode: block b -> (tr, tc), tr <= tc
  const int b = blockIdx.x;
  int tr = (int)((2 * NTILE + 1 - sqrtf((float)((2 * NTILE + 1) * (2 * NTILE + 1)) - 8.0f * (float)b)) * 0.5f);
  while (tr * NTILE - tr * (tr - 1) / 2 > b) --tr;
  while ((tr + 1) * NTILE - (tr + 1) * tr / 2 <= b) ++tr;
  const int tc = tr + (b - (tr * NTILE - tr * (tr - 1) / 2));

  __shared__ alignas(16) unsigned short Bs[128 * 128];  // 32 KiB
  const int tid = threadIdx.x;
  const int wid = tid >> 6;
  const int lane = tid & 63;
  const int wm = wid >> 2, wn = wid & 3;  // 2x4 waves: 64x32 output each
  const int lrow = lane & 15;
  const int kgrp = lane >> 4;

  // ---- stage B tile into LDS (swizzled) ----
  if constexpr (FROM_BF16) {
    const unsigned char* srcB = (const unsigned char*)src + (size_t)tc * 32768;
#pragma unroll
    for (int it = 0; it < 4; ++it) {
      int p = (it * 512 + tid) * 16;
      int g = p ^ (((p >> 8) & 7) << 4);
      __builtin_amdgcn_global_load_lds((gptr_t)(srcB + g),
                                       (lptr_t)((unsigned char*)Bs + p), 16, 0, 0);
    }
  } else {
    const float4* srcB4 = (const float4*)((const float*)src + (size_t)tc * 16384);
#pragma unroll
    for (int it = 0; it < 8; ++it) {
      int idx = it * 512 + tid;  // float4 index within slab [0,4096)
      int L = idx * 8;
      int swz = L ^ (((L >> 8) & 7) << 4);
      float4 bb = srcB4[idx];
      ushort4 ob = {f2bf(bb.x * SQRT_LOG2E), f2bf(bb.y * SQRT_LOG2E),
                    f2bf(bb.z * SQRT_LOG2E), f2bf(bb.w * SQRT_LOG2E)};
      *reinterpret_cast<ushort4*>((unsigned char*)Bs + swz) = ob;
    }
  }
  __syncthreads();

  f32x4 acc[4][2];
#pragma unroll
  for (int a = 0; a < 4; ++a)
#pragma unroll
    for (int c = 0; c < 2; ++c) acc[a][c] = (f32x4){0.f, 0.f, 0.f, 0.f};

  // ---- K-loop: A from global (L2/L1), B from LDS ----
  if constexpr (FROM_BF16) {
    const unsigned char* pa = (const unsigned char*)src + (size_t)tr * 32768 +
                              (wm * 64 + lrow) * 256 + kgrp * 16;
#pragma unroll
    for (int ks = 0; ks < 4; ++ks) {
      bf16x8 af[4], bfr[2];
#pragma unroll
      for (int f = 0; f < 4; ++f)
        af[f] = *reinterpret_cast<const bf16x8*>(pa + f * 16 * 256 + ks * 64);
#pragma unroll
      for (int f = 0; f < 2; ++f) {
        int br = wn * 32 + f * 16 + lrow;
        int bb = (br * 256 + ks * 64 + kgrp * 16) ^ ((br & 7) << 4);
        bfr[f] = *reinterpret_cast<const bf16x8*>((const unsigned char*)Bs + bb);
      }
#pragma unroll
      for (int fm = 0; fm < 4; ++fm)
#pragma unroll
        for (int fn = 0; fn < 2; ++fn)
          acc[fm][fn] = __builtin_amdgcn_mfma_f32_16x16x32_bf16(af[fm], bfr[fn], acc[fm][fn], 0, 0, 0);
    }
  } else {
    const float* pa = (const float*)src + (size_t)tr * 16384 + (wm * 64 + lrow) * 128 + kgrp * 8;
#pragma unroll
    for (int ks = 0; ks < 4; ++ks) {
      bf16x8 af[4], bfr[2];
#pragma unroll
      for (int f = 0; f < 4; ++f) {
        float4 lo = *reinterpret_cast<const float4*>(pa + f * 16 * 128 + ks * 32);
        float4 hi = *reinterpret_cast<const float4*>(pa + f * 16 * 128 + ks * 32 + 4);
        ushort4 ulo = {f2bf(lo.x * SQRT_LOG2E), f2bf(lo.y * SQRT_LOG2E),
                       f2bf(lo.z * SQRT_LOG2E), f2bf(lo.w * SQRT_LOG2E)};
        ushort4 uhi = {f2bf(hi.x * SQRT_LOG2E), f2bf(hi.y * SQRT_LOG2E),
                       f2bf(hi.z * SQRT_LOG2E), f2bf(hi.w * SQRT_LOG2E)};
        struct { ushort4 a, b; } pack{ulo, uhi};
        af[f] = *reinterpret_cast<const bf16x8*>(&pack);
      }
#pragma unroll
      for (int f = 0; f < 2; ++f) {
        int br = wn * 32 + f * 16 + lrow;
        int bb = (br * 256 + ks * 64 + kgrp * 16) ^ ((br & 7) << 4);
        bfr[f] = *reinterpret_cast<const bf16x8*>((const unsigned char*)Bs + bb);
      }
#pragma unroll
      for (int fm = 0; fm < 4; ++fm)
#pragma unroll
        for (int fn = 0; fn < 2; ++fn)
          acc[fm][fn] = __builtin_amdgcn_mfma_f32_16x16x32_bf16(af[fm], bfr[fn], acc[fm][fn], 0, 0, 0);
    }
  }

  // ---- epilogue, log2 domain. C/D layout: col=lane&15, row=(lane>>4)*4+reg.
  float sm = 0.f, sp = 0.f;
  if (tr == tc) {
#pragma unroll
    for (int fm = 0; fm < 4; ++fm)
#pragma unroll
      for (int fn = 0; fn < 2; ++fn)
#pragma unroll
        for (int r = 0; r < 4; ++r) {
          float v = acc[fm][fn][r];
          int il = wm * 64 + fm * 16 + kgrp * 4 + r;
          int jl = wn * 32 + fn * 16 + lrow;
          if (il == jl) v = -v;
          sm += fmaxf(v, 0.f);
          float u = EXP2F(-fabsf(v));
          sp = fmaf(u, fmaf(u, QC1, QC0), sp);
        }
  } else {
#pragma unroll
    for (int fm = 0; fm < 4; ++fm)
#pragma unroll
      for (int fn = 0; fn < 2; ++fn)
#pragma unroll
        for (int r = 0; r < 4; ++r) {
          float v = acc[fm][fn][r];
          sm += fmaxf(v, 0.f);
          float u = EXP2F(-fabsf(v));
          sp = fmaf(u, fmaf(u, QC1, QC0), sp);
        }
    sm *= 2.f;  // symmetric twin tile
    sp *= 2.f;
  }

  float lsum = sm + sp;
#pragma unroll
  for (int off = 32; off > 0; off >>= 1) lsum += __shfl_down(lsum, off);

  if (lane == 0)
    atomicAdd(buckets + (((b << 3) + wid) & (NBUCKET - 1)) * BSTRIDE, lsum);
}

__global__ void finalize_kernel(const float* __restrict__ buckets, float* __restrict__ out) {
  float v = buckets[threadIdx.x * BSTRIDE];  // 64 threads, one wave
#pragma unroll
  for (int off = 32; off > 0; off >>= 1) v += __shfl_down(v, off);
  if (threadIdx.x == 0)
    out[0] = LN2F * (v * (1.0f / (float)N_DOCS) + 1.0f);  // accum in log2 units
}

extern "C" void kernel_launch(void* const* d_in, const int* in_sizes, int n_in,
                              void* d_out, int out_size, void* d_ws, size_t ws_size,
                              hipStream_t stream) {
  const float* E = (const float*)d_in[0];
  float* out = (float*)d_out;
  float* buckets = (float*)d_ws;  // 64 buckets * 64B = 4 KiB

  const size_t need = 8192 + (size_t)N_DOCS * DIM * sizeof(unsigned short);  // ~4 MiB
  if (ws_size >= need) {
    unsigned short* ebf = (unsigned short*)((char*)d_ws + 8192);
    cast_kernel<<<(N_DOCS * DIM / 4) / 256, 256, 0, stream>>>(E, ebf, buckets);
    loss_kernel<true><<<NTRI, 512, 0, stream>>>(ebf, buckets);
  } else {
    (void)hipMemsetAsync(buckets, 0, NBUCKET * BSTRIDE * sizeof(float), stream);
    loss_kernel<false><<<NTRI, 512, 0, stream>>>(E, buckets);
  }
  finalize_kernel<<<1, 64, 0, stream>>>(buckets, out);
}